// Round 5
// baseline (160.698 us; speedup 1.0000x reference)
//
#include <hip/hip_runtime.h>
#include <hip/hip_bf16.h>

#define NUM_MOL 1024
#define KEHALF 7.199822675975274f
#define RCUT 10.0f

// Clang-native vector types (accepted by __builtin_nontemporal_load)
typedef int   vint4   __attribute__((ext_vector_type(4)));
typedef float vfloat4 __attribute__((ext_vector_type(4)));
typedef unsigned int vuint2 __attribute__((ext_vector_type(2)));

__device__ __forceinline__ float softplus_f(float x) {
    return (x > 20.0f) ? x : log1pf(__expf(x));
}

// ---------------------------------------------------------------------------
// Prep: per-atom packed 8B table  {bits(Z^softplus(apow)), mol<<8 | Z}
// ---------------------------------------------------------------------------
__global__ void zbl_prep_kernel(const float* __restrict__ Z,
                                const int* __restrict__ idx_m,
                                const float* __restrict__ apow,
                                vuint2* __restrict__ atab, int N) {
    int n = blockIdx.x * blockDim.x + threadIdx.x;
    if (n >= N) return;
    float p = softplus_f(apow[0]);
    float z = Z[n];
    float zp = __powf(z, p);
    unsigned zi = (unsigned)z;            // exact (1..94)
    unsigned m  = (unsigned)idx_m[n];     // < 1024
    vuint2 v; v.x = __float_as_uint(zp); v.y = (m << 8) | zi;
    atab[n] = v;
}

// ---------------------------------------------------------------------------
// Per-edge math (registers only; one LDS atomic at the end)
// ---------------------------------------------------------------------------
__device__ __forceinline__ void do_edge(
    float x, float yy, float zz, vuint2 ai, vuint2 aj,
    float sp_adiv, float sa0, float sa1, float sa2, float sa3,
    float c0, float c1, float c2, float c3, float* bins)
{
    const float d2 = x * x + yy * yy + zz * zz;
    const float inv = rsqrtf(d2);
    const float d = d2 * inv;

    const float u = d * (1.0f / RCUT);
    const float u3 = u * u * u;
    float fc = 1.0f + u3 * (-10.0f + u * (15.0f - 6.0f * u));
    fc = (d < RCUT) ? fc : 0.0f;

    const float zpi = __uint_as_float(ai.x);
    const float zpj = __uint_as_float(aj.x);
    const float zizj = (float)((ai.y & 0xFFu) * (aj.y & 0xFFu));   // exact
    const int   mol  = (int)(ai.y >> 8);

    const float a = (zpi + zpj) * sp_adiv;
    const float ad = a * d;
    const float ft = c0 * __expf(-sa0 * ad) + c1 * __expf(-sa1 * ad)
                   + c2 * __expf(-sa2 * ad) + c3 * __expf(-sa3 * ad);

    const float ee = KEHALF * ft * fc * zizj * inv;
    atomicAdd(&bins[mol], ee);
}

// ---------------------------------------------------------------------------
// Main edge kernel: LDS histogram; nontemporal (no-allocate) table gathers.
// Epilogue: one global atomicAdd per (block,bin) — measured ~3 µs, cheaper
// than the two extra reduce dispatches (~15 µs launch overhead, R4).
// ---------------------------------------------------------------------------
__global__ __launch_bounds__(512, 6) void zbl_edge_kernel(
    const float* __restrict__ r_ij,
    const int* __restrict__ idx_i,
    const int* __restrict__ idx_j,
    const vuint2* __restrict__ atab,
    const float* __restrict__ adiv,
    const float* __restrict__ a_vector,
    const float* __restrict__ c_vector,
    float* __restrict__ y, int E)
{
    __shared__ float bins[NUM_MOL];
    for (int b = threadIdx.x; b < NUM_MOL; b += blockDim.x) bins[b] = 0.0f;
    __syncthreads();

    const float sp_adiv = softplus_f(adiv[0]);
    const float sa0 = softplus_f(a_vector[0]);
    const float sa1 = softplus_f(a_vector[1]);
    const float sa2 = softplus_f(a_vector[2]);
    const float sa3 = softplus_f(a_vector[3]);
    float c0 = softplus_f(c_vector[0]);
    float c1 = softplus_f(c_vector[1]);
    float c2 = softplus_f(c_vector[2]);
    float c3 = softplus_f(c_vector[3]);
    const float cinv = 1.0f / (fabsf(c0) + fabsf(c1) + fabsf(c2) + fabsf(c3));
    c0 *= cinv; c1 *= cinv; c2 *= cinv; c3 *= cinv;

    const vfloat4* __restrict__ r4  = (const vfloat4*)r_ij;
    const vint4*   __restrict__ ii4 = (const vint4*)idx_i;
    const vint4*   __restrict__ jj4 = (const vint4*)idx_j;

    const int tid0   = blockIdx.x * blockDim.x + threadIdx.x;
    const int stride = gridDim.x * blockDim.x;
    const int G = E >> 2;

    for (int g = tid0; g < G; g += stride) {
        const vint4   vi = __builtin_nontemporal_load(&ii4[g]);
        const vint4   vj = __builtin_nontemporal_load(&jj4[g]);
        const vfloat4 ra = __builtin_nontemporal_load(&r4[3 * g + 0]);
        const vfloat4 rb = __builtin_nontemporal_load(&r4[3 * g + 1]);
        const vfloat4 rc = __builtin_nontemporal_load(&r4[3 * g + 2]);

        // EXPERIMENT (R5): nontemporal gathers — no line allocation/retention.
        // T2 (fill-BW wall) predicts big win; T1 (request-rate wall) predicts flat.
        const vuint2 ai0 = __builtin_nontemporal_load(&atab[vi.x]);
        const vuint2 ai1 = __builtin_nontemporal_load(&atab[vi.y]);
        const vuint2 ai2 = __builtin_nontemporal_load(&atab[vi.z]);
        const vuint2 ai3 = __builtin_nontemporal_load(&atab[vi.w]);
        const vuint2 aj0 = __builtin_nontemporal_load(&atab[vj.x]);
        const vuint2 aj1 = __builtin_nontemporal_load(&atab[vj.y]);
        const vuint2 aj2 = __builtin_nontemporal_load(&atab[vj.z]);
        const vuint2 aj3 = __builtin_nontemporal_load(&atab[vj.w]);

        do_edge(ra.x, ra.y, ra.z, ai0, aj0, sp_adiv, sa0, sa1, sa2, sa3, c0, c1, c2, c3, bins);
        do_edge(ra.w, rb.x, rb.y, ai1, aj1, sp_adiv, sa0, sa1, sa2, sa3, c0, c1, c2, c3, bins);
        do_edge(rb.z, rb.w, rc.x, ai2, aj2, sp_adiv, sa0, sa1, sa2, sa3, c0, c1, c2, c3, bins);
        do_edge(rc.y, rc.z, rc.w, ai3, aj3, sp_adiv, sa0, sa1, sa2, sa3, c0, c1, c2, c3, bins);
    }

    for (int e = (G << 2) + tid0; e < E; e += stride) {
        const vuint2 ai = atab[idx_i[e]];
        const vuint2 aj = atab[idx_j[e]];
        do_edge(r_ij[3 * e + 0], r_ij[3 * e + 1], r_ij[3 * e + 2],
                ai, aj, sp_adiv, sa0, sa1, sa2, sa3, c0, c1, c2, c3, bins);
    }

    __syncthreads();
    for (int b = threadIdx.x; b < NUM_MOL; b += blockDim.x) {
        const float v = bins[b];
        if (v != 0.0f) atomicAdd(&y[b], v);
    }
}

// ---------------------------------------------------------------------------
// Fallback (workspace too small): gather Z/idx_m directly, pow per edge
// ---------------------------------------------------------------------------
__global__ __launch_bounds__(256) void zbl_edge_kernel_nows(
    const float* __restrict__ r_ij,
    const int* __restrict__ idx_i,
    const int* __restrict__ idx_j,
    const float* __restrict__ Z,
    const int* __restrict__ idx_m,
    const float* __restrict__ adiv,
    const float* __restrict__ apow,
    const float* __restrict__ a_vector,
    const float* __restrict__ c_vector,
    float* __restrict__ y, int E)
{
    __shared__ float bins[NUM_MOL];
    for (int b = threadIdx.x; b < NUM_MOL; b += blockDim.x) bins[b] = 0.0f;
    __syncthreads();

    const float sp_apow = softplus_f(apow[0]);
    const float sp_adiv = softplus_f(adiv[0]);
    const float sa0 = softplus_f(a_vector[0]);
    const float sa1 = softplus_f(a_vector[1]);
    const float sa2 = softplus_f(a_vector[2]);
    const float sa3 = softplus_f(a_vector[3]);
    float c0 = softplus_f(c_vector[0]);
    float c1 = softplus_f(c_vector[1]);
    float c2 = softplus_f(c_vector[2]);
    float c3 = softplus_f(c_vector[3]);
    const float cinv = 1.0f / (fabsf(c0) + fabsf(c1) + fabsf(c2) + fabsf(c3));
    c0 *= cinv; c1 *= cinv; c2 *= cinv; c3 *= cinv;

    const int stride = gridDim.x * blockDim.x;
    for (int e = blockIdx.x * blockDim.x + threadIdx.x; e < E; e += stride) {
        const int i = idx_i[e];
        const int j = idx_j[e];
        const float zi = Z[i];
        const float zj = Z[j];
        const float x  = r_ij[3 * e + 0];
        const float yy = r_ij[3 * e + 1];
        const float zz = r_ij[3 * e + 2];
        const float d2 = x * x + yy * yy + zz * zz;
        const float inv = rsqrtf(d2);
        const float d = d2 * inv;

        const float u = d * (1.0f / RCUT);
        const float u3 = u * u * u;
        float fc = 1.0f + u3 * (-10.0f + u * (15.0f - 6.0f * u));
        fc = (d < RCUT) ? fc : 0.0f;

        const float a = (__powf(zi, sp_apow) + __powf(zj, sp_apow)) * sp_adiv;
        const float ad = a * d;
        const float ft = c0 * __expf(-sa0 * ad) + c1 * __expf(-sa1 * ad)
                       + c2 * __expf(-sa2 * ad) + c3 * __expf(-sa3 * ad);

        const float ee = KEHALF * ft * fc * zi * zj * inv;
        atomicAdd(&bins[idx_m[i]], ee);
    }

    __syncthreads();
    for (int b = threadIdx.x; b < NUM_MOL; b += blockDim.x) {
        const float v = bins[b];
        if (v != 0.0f) atomicAdd(&y[b], v);
    }
}

extern "C" void kernel_launch(void* const* d_in, const int* in_sizes, int n_in,
                              void* d_out, int out_size, void* d_ws, size_t ws_size,
                              hipStream_t stream) {
    // setup_inputs order: Z, r_ij, idx_i, idx_j, idx_m, adiv, apow, a_vector, c_vector
    const float* Z        = (const float*)d_in[0];
    const float* r_ij     = (const float*)d_in[1];
    const int*   idx_i    = (const int*)d_in[2];
    const int*   idx_j    = (const int*)d_in[3];
    const int*   idx_m    = (const int*)d_in[4];
    const float* adiv     = (const float*)d_in[5];
    const float* apow     = (const float*)d_in[6];
    const float* a_vector = (const float*)d_in[7];
    const float* c_vector = (const float*)d_in[8];
    float* y = (float*)d_out;

    const int N = in_sizes[0];
    const int E = in_sizes[1] / 3;

    // d_out is poisoned 0xAA before every launch -> zero it (graph-safe memset node)
    (void)hipMemsetAsync(y, 0, (size_t)out_size * sizeof(float), stream);

    const size_t atab_bytes = (size_t)N * sizeof(vuint2);
    if (ws_size >= atab_bytes) {
        vuint2* atab = (vuint2*)d_ws;
        zbl_prep_kernel<<<(N + 255) / 256, 256, 0, stream>>>(Z, idx_m, apow, atab, N);
        zbl_edge_kernel<<<1024, 512, 0, stream>>>(r_ij, idx_i, idx_j, atab,
                                                  adiv, a_vector, c_vector, y, E);
    } else {
        zbl_edge_kernel_nows<<<2048, 256, 0, stream>>>(r_ij, idx_i, idx_j, Z, idx_m,
                                                       adiv, apow, a_vector, c_vector, y, E);
    }
}

// Round 6
// 148.815 us; speedup vs baseline: 1.0798x; 1.0798x over previous
//
#include <hip/hip_runtime.h>
#include <hip/hip_bf16.h>

#define NUM_MOL 1024
#define KEHALF 7.199822675975274f
#define RCUT 10.0f

// Clang-native vector types (accepted by __builtin_nontemporal_load)
typedef int   vint4   __attribute__((ext_vector_type(4)));
typedef float vfloat4 __attribute__((ext_vector_type(4)));

__device__ __forceinline__ float softplus_f(float x) {
    return (x > 20.0f) ? x : log1pf(__expf(x));
}

// Agent-scope load -> bypasses the per-CU L1 (non-coherent), goes straight to L2.
// R6 experiment: avoids the TCP miss-handling/MSHR serialization on random gathers.
__device__ __forceinline__ unsigned long long load_agent_u64(const unsigned long long* p) {
    return __hip_atomic_load(p, __ATOMIC_RELAXED, __HIP_MEMORY_SCOPE_AGENT);
}

// ---------------------------------------------------------------------------
// Prep: per-atom packed 8B table  { low32: bits(Z^softplus(apow)), high32: mol<<8 | Z }
// ---------------------------------------------------------------------------
__global__ void zbl_prep_kernel(const float* __restrict__ Z,
                                const int* __restrict__ idx_m,
                                const float* __restrict__ apow,
                                unsigned long long* __restrict__ atab, int N) {
    int n = blockIdx.x * blockDim.x + threadIdx.x;
    if (n >= N) return;
    float p = softplus_f(apow[0]);
    float z = Z[n];
    float zp = __powf(z, p);
    unsigned zi = (unsigned)z;            // exact (1..94)
    unsigned m  = (unsigned)idx_m[n];     // < 1024
    unsigned long long v = ((unsigned long long)((m << 8) | zi) << 32)
                         | (unsigned long long)__float_as_uint(zp);
    atab[n] = v;
}

// ---------------------------------------------------------------------------
// Per-edge math (registers only; one LDS atomic at the end).
// KEHALF is pre-folded into c0..c3 by the caller.
// ---------------------------------------------------------------------------
__device__ __forceinline__ void do_edge(
    float x, float yy, float zz, unsigned long long ai, unsigned long long aj,
    float sp_adiv, float sa0, float sa1, float sa2, float sa3,
    float c0, float c1, float c2, float c3, float* bins)
{
    const float d2 = x * x + yy * yy + zz * zz;
    const float inv = rsqrtf(d2);
    const float d = d2 * inv;

    const float u = d * (1.0f / RCUT);
    const float u3 = u * u * u;
    float fc = 1.0f + u3 * (-10.0f + u * (15.0f - 6.0f * u));
    fc = (d < RCUT) ? fc : 0.0f;

    const unsigned hi_i = (unsigned)(ai >> 32);
    const unsigned hi_j = (unsigned)(aj >> 32);
    const float zpi = __uint_as_float((unsigned)ai);
    const float zpj = __uint_as_float((unsigned)aj);
    const float zizj = (float)((hi_i & 0xFFu) * (hi_j & 0xFFu));   // exact
    const int   mol  = (int)(hi_i >> 8);

    const float a = (zpi + zpj) * sp_adiv;
    const float ad = a * d;
    const float ft = c0 * __expf(-sa0 * ad) + c1 * __expf(-sa1 * ad)
                   + c2 * __expf(-sa2 * ad) + c3 * __expf(-sa3 * ad);

    const float ee = ft * fc * zizj * inv;     // KEHALF folded into c_k
    atomicAdd(&bins[mol], ee);
}

// ---------------------------------------------------------------------------
// Main edge kernel: LDS histogram; L1-BYPASS (agent-scope) table gathers.
// Epilogue: one global atomicAdd per (block,bin) — cheaper than extra
// reduce dispatches (R4: tree cost +15 µs launch overhead, same kernel time).
// ---------------------------------------------------------------------------
__global__ __launch_bounds__(512, 6) void zbl_edge_kernel(
    const float* __restrict__ r_ij,
    const int* __restrict__ idx_i,
    const int* __restrict__ idx_j,
    const unsigned long long* __restrict__ atab,
    const float* __restrict__ adiv,
    const float* __restrict__ a_vector,
    const float* __restrict__ c_vector,
    float* __restrict__ y, int E)
{
    __shared__ float bins[NUM_MOL];
    for (int b = threadIdx.x; b < NUM_MOL; b += blockDim.x) bins[b] = 0.0f;
    __syncthreads();

    const float sp_adiv = softplus_f(adiv[0]);
    const float sa0 = softplus_f(a_vector[0]);
    const float sa1 = softplus_f(a_vector[1]);
    const float sa2 = softplus_f(a_vector[2]);
    const float sa3 = softplus_f(a_vector[3]);
    float c0 = softplus_f(c_vector[0]);
    float c1 = softplus_f(c_vector[1]);
    float c2 = softplus_f(c_vector[2]);
    float c3 = softplus_f(c_vector[3]);
    const float cinv = KEHALF / (fabsf(c0) + fabsf(c1) + fabsf(c2) + fabsf(c3));
    c0 *= cinv; c1 *= cinv; c2 *= cinv; c3 *= cinv;    // KEHALF folded in

    const vfloat4* __restrict__ r4  = (const vfloat4*)r_ij;
    const vint4*   __restrict__ ii4 = (const vint4*)idx_i;
    const vint4*   __restrict__ jj4 = (const vint4*)idx_j;

    const int tid0   = blockIdx.x * blockDim.x + threadIdx.x;
    const int stride = gridDim.x * blockDim.x;
    const int G = E >> 2;

    for (int g = tid0; g < G; g += stride) {
        const vint4   vi = __builtin_nontemporal_load(&ii4[g]);
        const vint4   vj = __builtin_nontemporal_load(&jj4[g]);
        const vfloat4 ra = __builtin_nontemporal_load(&r4[3 * g + 0]);
        const vfloat4 rb = __builtin_nontemporal_load(&r4[3 * g + 1]);
        const vfloat4 rc = __builtin_nontemporal_load(&r4[3 * g + 2]);

        // 8 independent L1-bypass gathers, all in flight before first use
        const unsigned long long ai0 = load_agent_u64(&atab[vi.x]);
        const unsigned long long ai1 = load_agent_u64(&atab[vi.y]);
        const unsigned long long ai2 = load_agent_u64(&atab[vi.z]);
        const unsigned long long ai3 = load_agent_u64(&atab[vi.w]);
        const unsigned long long aj0 = load_agent_u64(&atab[vj.x]);
        const unsigned long long aj1 = load_agent_u64(&atab[vj.y]);
        const unsigned long long aj2 = load_agent_u64(&atab[vj.z]);
        const unsigned long long aj3 = load_agent_u64(&atab[vj.w]);

        do_edge(ra.x, ra.y, ra.z, ai0, aj0, sp_adiv, sa0, sa1, sa2, sa3, c0, c1, c2, c3, bins);
        do_edge(ra.w, rb.x, rb.y, ai1, aj1, sp_adiv, sa0, sa1, sa2, sa3, c0, c1, c2, c3, bins);
        do_edge(rb.z, rb.w, rc.x, ai2, aj2, sp_adiv, sa0, sa1, sa2, sa3, c0, c1, c2, c3, bins);
        do_edge(rc.y, rc.z, rc.w, ai3, aj3, sp_adiv, sa0, sa1, sa2, sa3, c0, c1, c2, c3, bins);
    }

    for (int e = (G << 2) + tid0; e < E; e += stride) {
        const unsigned long long ai = load_agent_u64(&atab[idx_i[e]]);
        const unsigned long long aj = load_agent_u64(&atab[idx_j[e]]);
        do_edge(r_ij[3 * e + 0], r_ij[3 * e + 1], r_ij[3 * e + 2],
                ai, aj, sp_adiv, sa0, sa1, sa2, sa3, c0, c1, c2, c3, bins);
    }

    __syncthreads();
    for (int b = threadIdx.x; b < NUM_MOL; b += blockDim.x) {
        const float v = bins[b];
        if (v != 0.0f) atomicAdd(&y[b], v);
    }
}

// ---------------------------------------------------------------------------
// Fallback (workspace too small): gather Z/idx_m directly, pow per edge
// ---------------------------------------------------------------------------
__global__ __launch_bounds__(256) void zbl_edge_kernel_nows(
    const float* __restrict__ r_ij,
    const int* __restrict__ idx_i,
    const int* __restrict__ idx_j,
    const float* __restrict__ Z,
    const int* __restrict__ idx_m,
    const float* __restrict__ adiv,
    const float* __restrict__ apow,
    const float* __restrict__ a_vector,
    const float* __restrict__ c_vector,
    float* __restrict__ y, int E)
{
    __shared__ float bins[NUM_MOL];
    for (int b = threadIdx.x; b < NUM_MOL; b += blockDim.x) bins[b] = 0.0f;
    __syncthreads();

    const float sp_apow = softplus_f(apow[0]);
    const float sp_adiv = softplus_f(adiv[0]);
    const float sa0 = softplus_f(a_vector[0]);
    const float sa1 = softplus_f(a_vector[1]);
    const float sa2 = softplus_f(a_vector[2]);
    const float sa3 = softplus_f(a_vector[3]);
    float c0 = softplus_f(c_vector[0]);
    float c1 = softplus_f(c_vector[1]);
    float c2 = softplus_f(c_vector[2]);
    float c3 = softplus_f(c_vector[3]);
    const float cinv = 1.0f / (fabsf(c0) + fabsf(c1) + fabsf(c2) + fabsf(c3));
    c0 *= cinv; c1 *= cinv; c2 *= cinv; c3 *= cinv;

    const int stride = gridDim.x * blockDim.x;
    for (int e = blockIdx.x * blockDim.x + threadIdx.x; e < E; e += stride) {
        const int i = idx_i[e];
        const int j = idx_j[e];
        const float zi = Z[i];
        const float zj = Z[j];
        const float x  = r_ij[3 * e + 0];
        const float yy = r_ij[3 * e + 1];
        const float zz = r_ij[3 * e + 2];
        const float d2 = x * x + yy * yy + zz * zz;
        const float inv = rsqrtf(d2);
        const float d = d2 * inv;

        const float u = d * (1.0f / RCUT);
        const float u3 = u * u * u;
        float fc = 1.0f + u3 * (-10.0f + u * (15.0f - 6.0f * u));
        fc = (d < RCUT) ? fc : 0.0f;

        const float a = (__powf(zi, sp_apow) + __powf(zj, sp_apow)) * sp_adiv;
        const float ad = a * d;
        const float ft = c0 * __expf(-sa0 * ad) + c1 * __expf(-sa1 * ad)
                       + c2 * __expf(-sa2 * ad) + c3 * __expf(-sa3 * ad);

        const float ee = KEHALF * ft * fc * zi * zj * inv;
        atomicAdd(&bins[idx_m[i]], ee);
    }

    __syncthreads();
    for (int b = threadIdx.x; b < NUM_MOL; b += blockDim.x) {
        const float v = bins[b];
        if (v != 0.0f) atomicAdd(&y[b], v);
    }
}

extern "C" void kernel_launch(void* const* d_in, const int* in_sizes, int n_in,
                              void* d_out, int out_size, void* d_ws, size_t ws_size,
                              hipStream_t stream) {
    // setup_inputs order: Z, r_ij, idx_i, idx_j, idx_m, adiv, apow, a_vector, c_vector
    const float* Z        = (const float*)d_in[0];
    const float* r_ij     = (const float*)d_in[1];
    const int*   idx_i    = (const int*)d_in[2];
    const int*   idx_j    = (const int*)d_in[3];
    const int*   idx_m    = (const int*)d_in[4];
    const float* adiv     = (const float*)d_in[5];
    const float* apow     = (const float*)d_in[6];
    const float* a_vector = (const float*)d_in[7];
    const float* c_vector = (const float*)d_in[8];
    float* y = (float*)d_out;

    const int N = in_sizes[0];
    const int E = in_sizes[1] / 3;

    // d_out is poisoned 0xAA before every launch -> zero it (graph-safe memset node)
    (void)hipMemsetAsync(y, 0, (size_t)out_size * sizeof(float), stream);

    const size_t atab_bytes = (size_t)N * sizeof(unsigned long long);
    if (ws_size >= atab_bytes) {
        unsigned long long* atab = (unsigned long long*)d_ws;
        zbl_prep_kernel<<<(N + 255) / 256, 256, 0, stream>>>(Z, idx_m, apow, atab, N);
        zbl_edge_kernel<<<1024, 512, 0, stream>>>(r_ij, idx_i, idx_j, atab,
                                                  adiv, a_vector, c_vector, y, E);
    } else {
        zbl_edge_kernel_nows<<<2048, 256, 0, stream>>>(r_ij, idx_i, idx_j, Z, idx_m,
                                                       adiv, apow, a_vector, c_vector, y, E);
    }
}